// Round 6
// baseline (304.260 us; speedup 1.0000x reference)
//
#include <hip/hip_runtime.h>
#include <math.h>

// RetNetRelPosDeform2D: B=8,H=8,N1=N2=32,slen=1024,D=64
// Outputs (fp32, flat-concatenated):
//   sin_q [8,8,1024,64]  @ 0
//   cos_q [8,8,1024,64]  @ 4194304
//   sin_k [1024,64]      @ 8388608
//   cos_k [1024,64]      @ 8454144
//   mask  [8,8,1024,1024]@ 8519680
#define OFF_COSQ  4194304
#define OFF_SINK  8388608
#define OFF_COSK  8454144
#define OFF_MASK  8519680
#define NROWS     65536   // B*H*slen
#define ROWS_PER_WAVE 4

typedef float floatx4 __attribute__((ext_vector_type(4)));

// One wave per FOUR consecutive query rows (same bh, same i, j=j0..j0+3).
// The four rows' serial dep chains (offsets load -> exp -> butterfly -> rsqrt)
// are independent -> ILP overlaps them; preamble amortizes 4x; 64 float4
// nt-stores per wave keep the store queue dense.
__global__ __launch_bounds__(256) void retnet_fused_kernel(
    const float* __restrict__ offsets,   // [B,H,32,32,2]
    const float* __restrict__ angle,     // [64]
    const float* __restrict__ decay,     // [8]
    float* __restrict__ out)
{
    const int wave = blockIdx.x * 4 + (threadIdx.x >> 6);
    const int lane = threadIdx.x & 63;
    const int r0   = wave * ROWS_PER_WAVE;       // first row of this wave

    const int bh = r0 >> 10;        // identical for all 4 rows (1024 % 4 == 0)
    const int h  = bh & 7;
    const float dec = decay[h];
    const float ang = angle[lane];

    // ---- per-row deformed indices ----
    float i1q[ROWS_PER_WAVE], i2q[ROWS_PER_WAVE];
    #pragma unroll
    for (int t = 0; t < ROWS_PER_WAVE; ++t) {
        const int r = r0 + t;
        const int s = r & 1023;
        const int i = s >> 5;
        const int j = s & 31;
        i1q[t] = (float)i + offsets[(r << 1) + 0];
        i2q[t] = (float)j + offsets[(r << 1) + 1];
    }

    // ---- sin_q / cos_q ----
    #pragma unroll
    for (int t = 0; t < ROWS_PER_WAVE; ++t) {
        const int r = r0 + t;
        float sq, cq;
        __sincosf((i1q[t] + i2q[t]) * ang, &sq, &cq);
        __builtin_nontemporal_store(sq, &out[(size_t)r * 64 + lane]);
        __builtin_nontemporal_store(cq, &out[OFF_COSQ + (size_t)r * 64 + lane]);
    }

    // ---- sin_k / cos_k: only rows with bh==0 emit them ----
    if (bh == 0) {
        #pragma unroll
        for (int t = 0; t < ROWS_PER_WAVE; ++t) {
            const int s = r0 + t;           // == r for bh==0
            const int i = s >> 5;
            const int j = s & 31;
            float sk, ck;
            __sincosf((float)(i + j) * ang, &sk, &ck);
            __builtin_nontemporal_store(sk, &out[OFF_SINK + (size_t)s * 64 + lane]);
            __builtin_nontemporal_store(ck, &out[OFF_COSK + (size_t)s * 64 + lane]);
        }
    }

    // ---- per-row normalization: sum1*sum2 via distributed exp + butterfly ----
    float invnorm[ROWS_PER_WAVE];
    {
        const int l5 = lane & 31;
        float v[ROWS_PER_WAVE], sum[ROWS_PER_WAVE];
        #pragma unroll
        for (int t = 0; t < ROWS_PER_WAVE; ++t) {
            const float base = (lane < 32) ? i1q[t] : i2q[t];
            v[t]   = __expf(dec * fabsf(base - (float)l5));
            sum[t] = v[t];
        }
        // interleaved butterflies: 4 independent chains overlap
        #pragma unroll
        for (int m = 16; m >= 1; m >>= 1) {
            #pragma unroll
            for (int t = 0; t < ROWS_PER_WAVE; ++t)
                sum[t] += __shfl_xor(sum[t], m, 64);
        }
        #pragma unroll
        for (int t = 0; t < ROWS_PER_WAVE; ++t) {
            const float s1 = __shfl(sum[t], 0, 64);
            const float s2 = __shfl(sum[t], 32, 64);
            invnorm[t] = rsqrtf(s1 * s2);
        }
    }

    // ---- mask rows: recompute tile factors (trans pipe has big slack) ----
    // float4 index f = k*64+lane -> ii = k*8 + (lane>>3), jj = (lane&7)*4 + c
    const int jj0 = (lane & 7) * 4;
    const int ii0 = lane >> 3;
    #pragma unroll
    for (int t = 0; t < ROWS_PER_WAVE; ++t) {
        const int r = r0 + t;
        floatx4 e2q;
        e2q.x = __expf(dec * fabsf(i2q[t] - (float)(jj0 + 0))) * invnorm[t];
        e2q.y = __expf(dec * fabsf(i2q[t] - (float)(jj0 + 1))) * invnorm[t];
        e2q.z = __expf(dec * fabsf(i2q[t] - (float)(jj0 + 2))) * invnorm[t];
        e2q.w = __expf(dec * fabsf(i2q[t] - (float)(jj0 + 3))) * invnorm[t];

        floatx4* mrow = (floatx4*)(out + OFF_MASK + (size_t)r * 1024);
        #pragma unroll
        for (int k = 0; k < 4; ++k) {
            const float e1 = __expf(dec * fabsf(i1q[t] - (float)(k * 8 + ii0)));
            __builtin_nontemporal_store(e2q * e1, &mrow[k * 64 + lane]);
        }
    }
}

extern "C" void kernel_launch(void* const* d_in, const int* in_sizes, int n_in,
                              void* d_out, int out_size, void* d_ws, size_t ws_size,
                              hipStream_t stream) {
    // inputs: [0]=slen (int, unused), [1]=offsets fp32 [8,8,32,32,2],
    //         [2]=angle fp32 [64], [3]=decay fp32 [8]
    const float* offsets = (const float*)d_in[1];
    const float* angle   = (const float*)d_in[2];
    const float* decay   = (const float*)d_in[3];
    float* out = (float*)d_out;

    const int blocks = NROWS / ROWS_PER_WAVE / 4;  // 4 waves/block, 4 rows/wave
    retnet_fused_kernel<<<blocks, 256, 0, stream>>>(offsets, angle, decay, out);
}